// Round 3
// baseline (1916.562 us; speedup 1.0000x reference)
//
#include <hip/hip_runtime.h>

// MultiHeadElman, two-phase:
//  Phase 1 (parallel, memory-bound): wx[t,b,h,i] = dot(Wx[h,i,:], x[t,b,h,:]) + bias[h,i]
//           staged IN-PLACE into d_out (ys region, identical [T,B,H,HD] layout).
//  Phase 2 (latency-bound scan): 1 wave per (b,h) chain, 4096 steps of
//           h = softsign(R@h + wx_t). wx read back from d_out (16-deep register
//           ring, 1 float/lane/step), ys overwrites the same addresses >=16
//           steps behind the reads. Redistribution of h via 16x ds_bpermute
//           (register crossbar, no LDS round-trip, no barrier).

constexpr int T_STEPS = 4096;
constexpr int B_SZ    = 4;
constexpr int D_SZ    = 2048;
constexpr int H_SZ    = 64;
constexpr int HD      = 32;
constexpr long STRIDE_T = (long)B_SZ * D_SZ;   // 8192 floats per t

// ---------------- Phase 1: wx precompute ----------------
// One wave covers 2 heads (lane p = l>>5 selects head, i = l&31 the row) for a
// TT-step chunk; each lane computes a full 32-j dot (no cross-lane combine).
constexpr int TT = 64;   // t-steps per wave

__global__ __launch_bounds__(256)
void wx_precompute(const float* __restrict__ x,
                   const float* __restrict__ Wx,
                   const float* __restrict__ bias,
                   float* __restrict__ out)
{
    const int l  = threadIdx.x & 63;
    const int i  = l & 31;
    const int p  = l >> 5;                       // which head of the pair
    const int gw = blockIdx.x * 4 + (threadIdx.x >> 6);
    const int chunk = gw & (T_STEPS / TT - 1);   // 0..63, fastest: waves in a
    const int rest  = gw >> 6;                   // block share (b, head-pair)
    const int b  = rest >> 5;                    // 0..3
    const int hp = rest & 31;                    // head-pair 0..31
    const int h  = hp * 2 + p;                   // this lane's head

    // weights: full row Wx[h][i][0..31] (32 regs) + bias
    float w32[32];
    {
        const float4* Wp = (const float4*)(Wx + ((h * HD + i) * HD));
#pragma unroll
        for (int q = 0; q < 8; ++q) {
            float4 v = Wp[q];
            w32[4*q+0] = v.x; w32[4*q+1] = v.y; w32[4*q+2] = v.z; w32[4*q+3] = v.w;
        }
    }
    const float bi = bias[h * HD + i];

    const long t0 = (long)chunk * TT;
    const float* xp = x   + t0 * STRIDE_T + (long)b * D_SZ + h * HD;
    float*       op = out + t0 * STRIDE_T + (long)b * D_SZ + hp * 2 * HD + l;

    for (int t = 0; t < TT; ++t) {
        float xa[32];
        {
            const float4* xv = (const float4*)xp;
#pragma unroll
            for (int q = 0; q < 8; ++q) {
                float4 v = xv[q];
                xa[4*q+0] = v.x; xa[4*q+1] = v.y; xa[4*q+2] = v.z; xa[4*q+3] = v.w;
            }
        }
        float a0 = w32[0] * xa[0];
        float a1 = w32[1] * xa[1];
        float a2 = w32[2] * xa[2];
        float a3 = w32[3] * xa[3];
#pragma unroll
        for (int q = 1; q < 8; ++q) {
            a0 = fmaf(w32[4*q+0], xa[4*q+0], a0);
            a1 = fmaf(w32[4*q+1], xa[4*q+1], a1);
            a2 = fmaf(w32[4*q+2], xa[4*q+2], a2);
            a3 = fmaf(w32[4*q+3], xa[4*q+3], a3);
        }
        op[0] = ((a0 + a1) + (a2 + a3)) + bi;
        xp += STRIDE_T;
        op += STRIDE_T;
    }
}

// ---------------- Phase 2: sequential scan ----------------
constexpr int PF = 16;   // wx prefetch depth (register ring), T_STEPS % PF == 0

__global__ __launch_bounds__(64, 1)
void elman_scan(const float* __restrict__ R,
                const float* __restrict__ h0,
                float* __restrict__ out)   // wx in, ys out (in-place)
{
    const int l = threadIdx.x & 63;
    const int i = l & 31;                 // output row
    const int p = l >> 5;                 // j-half
    const int h = blockIdx.x & (H_SZ - 1);
    const int b = blockIdx.x >> 6;

    // R row slice (16 regs)
    float r[16], hj[16];
    {
        const float4* Rp = (const float4*)(R + ((h * HD + i) * HD + 16 * p));
#pragma unroll
        for (int q = 0; q < 4; ++q) {
            float4 v = Rp[q];
            r[4*q+0] = v.x; r[4*q+1] = v.y; r[4*q+2] = v.z; r[4*q+3] = v.w;
        }
    }
    // initial h slice
    {
        const float4* hp = (const float4*)(h0 + ((b * H_SZ + h) * HD + 16 * p));
#pragma unroll
        for (int q = 0; q < 4; ++q) {
            float4 v = hp[q];
            hj[4*q+0] = v.x; hj[4*q+1] = v.y; hj[4*q+2] = v.z; hj[4*q+3] = v.w;
        }
    }

    // all 64 lanes read the same per-row wx element (both halves: row i)
    const float* wxb_base = out + (long)b * D_SZ + h * HD + i;
    float*       op       = out + (long)b * D_SZ + h * HD + i;

    // 16-deep register ring of wx
    float wxb[PF];
#pragma unroll
    for (int k = 0; k < PF; ++k) wxb[k] = wxb_base[(long)k * STRIDE_T];
    const float* wxp = wxb_base + (long)PF * STRIDE_T;   // points at step tb+16

    // bpermute byte addresses: lane (i,p) pulls rows 16p+k from lanes 16p+k
    const int bpb = p * 64;

    float hn = 0.0f;

    for (int tb = 0; tb < T_STEPS; tb += PF) {
        const bool do_pf = (tb + PF < T_STEPS);
#pragma unroll
        for (int k = 0; k < PF; ++k) {
            const float mywx = wxb[k];
            if (do_pf) wxb[k] = wxp[(long)k * STRIDE_T];   // refill for step tb+k+PF

            // R.h partial over own j-half
            float a0 = r[0] * hj[0];
            float a1 = r[1] * hj[1];
            float a2 = r[2] * hj[2];
            float a3 = r[3] * hj[3];
#pragma unroll
            for (int q = 1; q < 4; ++q) {
                a0 = fmaf(r[4*q+0], hj[4*q+0], a0);
                a1 = fmaf(r[4*q+1], hj[4*q+1], a1);
                a2 = fmaf(r[4*q+2], hj[4*q+2], a2);
                a3 = fmaf(r[4*q+3], hj[4*q+3], a3);
            }
            float acc = (a0 + a1) + (a2 + a3);
            acc += __shfl_xor(acc, 32, 64);      // combine j-halves (both halves get full sum)
            const float pre = acc + mywx;        // wx already includes bias
            hn = pre * __builtin_amdgcn_rcpf(1.0f + fabsf(pre));

            if (l < HD) op[0] = hn;              // ys (overwrites consumed wx)

            // redistribute: hj[k2] = hn of row 16p+k2, pulled from lane 16p+k2
            const int hni = __float_as_int(hn);
#pragma unroll
            for (int k2 = 0; k2 < 16; ++k2) {
                hj[k2] = __int_as_float(__builtin_amdgcn_ds_bpermute(bpb + 4 * k2, hni));
            }

            op += STRIDE_T;
        }
        wxp += (long)PF * STRIDE_T;
    }

    // h_final after ys
    if (l < HD) {
        out[(long)T_STEPS * STRIDE_T + (b * H_SZ + h) * HD + i] = hn;
    }
}

extern "C" void kernel_launch(void* const* d_in, const int* in_sizes, int n_in,
                              void* d_out, int out_size, void* d_ws, size_t ws_size,
                              hipStream_t stream) {
    const float* x    = (const float*)d_in[0];
    const float* h0   = (const float*)d_in[1];
    const float* R    = (const float*)d_in[2];
    const float* Wx   = (const float*)d_in[3];
    const float* bias = (const float*)d_in[4];
    float* out = (float*)d_out;

    // Phase 1: 8192 waves = (T/TT=64) x (B=4) x (H/2=32), 4 waves/block
    wx_precompute<<<dim3(2048), dim3(256), 0, stream>>>(x, Wx, bias, out);
    // Phase 2: one wave per (b,h) chain
    elman_scan<<<dim3(B_SZ * H_SZ), dim3(64), 0, stream>>>(R, h0, out);
}

// Round 6
// 955.213 us; speedup vs baseline: 2.0064x; 2.0064x over previous
//
#include <hip/hip_runtime.h>

// MultiHeadElman, monolithic scan (R6): proven-primitive version of R4/R5.
// h_{t+1} = softsign(R@h + Wx@x_t + bias), T=4096, 256 chains (b,h),
// one 64-lane wave per chain. Lane layout: q = l&15, g = l>>4.
//   g0: rows 0-15 /j-lo   g1: rows 16-31 /j-hi
//   g2: rows 0-15 /j-hi   g3: rows 16-31 /j-lo
// After the cross-half combine every lane holds hn of its own row, so
// operand j = joff + ((q+k)&15) of the dot lives in lane (joff+((q+k)&15)).
// Both h and x dot-operands are gathered via ds_bpermute with precomputed
// byte addresses (proven in R3); halves combined via __shfl_xor(s,32)
// (proven in R1/R2). No DPP, no permlane_swap, no inline asm.

constexpr int T_STEPS = 4096;
constexpr int B_SZ    = 4;
constexpr int D_SZ    = 2048;
constexpr int H_SZ    = 64;
constexpr int HD      = 32;
constexpr long ST     = (long)B_SZ * D_SZ;   // 8192 floats per t
constexpr int PF      = 16;                  // x prefetch depth (reg ring)

__global__ __launch_bounds__(64, 1)
void elman_fused(const float* __restrict__ x,
                 const float* __restrict__ h0,
                 const float* __restrict__ R,
                 const float* __restrict__ Wx,
                 const float* __restrict__ bias,
                 float* __restrict__ out)
{
    const int l = threadIdx.x & 63;
    const int q = l & 15;
    const int g = l >> 4;
    const int joff = (g == 1 || g == 2) ? 16 : 0;   // j-half this lane covers
    const int row  = (g & 1) ? 16 + q : q;          // output row this lane owns
    const int h = blockIdx.x & (H_SZ - 1);
    const int b = blockIdx.x >> 6;

    // bpermute byte addresses + weights, both in rotation order k -> j(k)
    int   ba[16];
    float rw[16], ww[16];
    {
        const float* Rrow = R  + (h * HD + row) * HD;
        const float* Wrow = Wx + (h * HD + row) * HD;
#pragma unroll
        for (int k = 0; k < 16; ++k) {
            const int j = joff + ((q + k) & 15);
            ba[k] = j * 4;          // h[j]/x[j] live in lane j (lanes 0..31)
            rw[k] = Rrow[j];
            ww[k] = Wrow[j];
        }
    }
    // each j-half contributes bias/2; combine then carries the full bias and
    // partner lanes produce bit-identical pre (commutative add) -> safe
    // duplicate stores without exec-mask games.
    const float bias_half = 0.5f * bias[h * HD + row];

    float hn = h0[(b * H_SZ + h) * HD + row];       // own row's h

    const float* xbase = x   + (long)b * D_SZ + h * HD + joff + q;
    float*       op    = out + (long)b * D_SZ + h * HD + row;

    // x register ring: PF steps in flight, 1 dword/lane/step
    float xb[PF];
#pragma unroll
    for (int k = 0; k < PF; ++k) xb[k] = xbase[(long)k * ST];

    for (int tb = 0; tb < T_STEPS; tb += PF) {
        // last block redundantly reloads itself (in-bounds, values unused)
        const int tnext = (tb + PF < T_STEPS) ? (tb + PF) : tb;
        const float* xn = xbase + (long)tnext * ST;

#pragma unroll
        for (int k = 0; k < PF; ++k) {
            const float xd = xb[k];
            const int   xi = __float_as_int(xd);
            const int   hi = __float_as_int(hn);

            // gather h operands (critical chain: depends on hn)
            float hr[16];
#pragma unroll
            for (int m = 0; m < 16; ++m)
                hr[m] = __int_as_float(__builtin_amdgcn_ds_bpermute(ba[m], hi));

            // gather x operands (xd was ready PF steps ago -> off-chain;
            // lane's own term is m==0: ba[0] = joff+q = own lane)
            float xr[16];
            xr[0] = xd;
#pragma unroll
            for (int m = 1; m < 16; ++m)
                xr[m] = __int_as_float(__builtin_amdgcn_ds_bpermute(ba[m], xi));

            // 32 FMAs into 4 accumulators (W terms first: independent of hr)
            float a0 = fmaf(ww[0], xr[0], bias_half);
            float a1 = ww[1] * xr[1];
            float a2 = ww[2] * xr[2];
            float a3 = ww[3] * xr[3];
#pragma unroll
            for (int t4 = 1; t4 < 4; ++t4) {
                a0 = fmaf(ww[4*t4+0], xr[4*t4+0], a0);
                a1 = fmaf(ww[4*t4+1], xr[4*t4+1], a1);
                a2 = fmaf(ww[4*t4+2], xr[4*t4+2], a2);
                a3 = fmaf(ww[4*t4+3], xr[4*t4+3], a3);
            }
#pragma unroll
            for (int t4 = 0; t4 < 4; ++t4) {
                a0 = fmaf(rw[4*t4+0], hr[4*t4+0], a0);
                a1 = fmaf(rw[4*t4+1], hr[4*t4+1], a1);
                a2 = fmaf(rw[4*t4+2], hr[4*t4+2], a2);
                a3 = fmaf(rw[4*t4+3], hr[4*t4+3], a3);
            }
            const float s = (a0 + a1) + (a2 + a3);

            // combine with complementary j-half (lane l^32) — proven idiom
            const float pre = s + __shfl_xor(s, 32, 64);

            // softsign via v_rcp_f32 (~1 ulp, recurrence contractive)
            hn = pre * __builtin_amdgcn_rcpf(1.0f + fabsf(pre));

            // all 64 lanes store; partner pairs write identical values
            op[0] = hn;
            op += ST;

            // refill ring slot k for step tnext + k (off the chain)
            xb[k] = xn[(long)k * ST];
        }
    }

    // h_final after ys (duplicate stores identical -> safe)
    out[(long)T_STEPS * ST + (b * H_SZ + h) * HD + row] = hn;
}

extern "C" void kernel_launch(void* const* d_in, const int* in_sizes, int n_in,
                              void* d_out, int out_size, void* d_ws, size_t ws_size,
                              hipStream_t stream) {
    const float* x    = (const float*)d_in[0];
    const float* h0   = (const float*)d_in[1];
    const float* R    = (const float*)d_in[2];
    const float* Wx   = (const float*)d_in[3];
    const float* bias = (const float*)d_in[4];
    float* out = (float*)d_out;

    elman_fused<<<dim3(B_SZ * H_SZ), dim3(64), 0, stream>>>(x, h0, R, Wx, bias, out);
}

// Round 7
// 918.711 us; speedup vs baseline: 2.0861x; 1.0397x over previous
//
#include <hip/hip_runtime.h>

// MultiHeadElman scan, R7: (i,p) layout + block-staged x through LDS.
// h_{t+1} = softsign(R@h + Wx@x_t + bias), T=4096, 256 chains (b,h),
// one 64-lane wave per chain. Lane l: i = l&31 (output row), p = l>>5
// (j-half). Per step:
//   - h operands: 16x ds_bpermute from lanes 16p+m (proven R6)   [on chain]
//   - x operands: 4x ds_read_b128 broadcast from LDS x-ring      [off chain]
//   - W-partials off-chain (x available a block early), R-partials on-chain,
//     combine halves via __shfl_xor(s,32) (proven R1/R2/R6).
// x staging (T14): per 16-step block, each lane does 2 global float4 loads
// (block top) and 2 ds_write_b128 (block bottom) into the other LDS buffer.
// Any compiler load-sinking exposes at most one ~900cy stall per 16 steps.

constexpr int T_STEPS = 4096;
constexpr int B_SZ    = 4;
constexpr int D_SZ    = 2048;
constexpr int H_SZ    = 64;
constexpr int HD      = 32;
constexpr long ST     = (long)B_SZ * D_SZ;   // 8192 floats per t
constexpr int BLK     = 16;                  // steps per staging block

__global__ __launch_bounds__(64, 1)
void elman_fused(const float* __restrict__ x,
                 const float* __restrict__ h0,
                 const float* __restrict__ R,
                 const float* __restrict__ Wx,
                 const float* __restrict__ bias,
                 float* __restrict__ out)
{
    const int l = threadIdx.x & 63;
    const int i = l & 31;                 // output row
    const int p = l >> 5;                 // j-half
    const int h = blockIdx.x & (H_SZ - 1);
    const int b = blockIdx.x >> 6;

    // weights, natural j-order: r[m] = R[h][i][16p+m], w[m] = Wx[h][i][16p+m]
    float r[16], w[16];
    {
        const float4* Rp = (const float4*)(R  + ((h * HD + i) * HD + 16 * p));
        const float4* Wp = (const float4*)(Wx + ((h * HD + i) * HD + 16 * p));
#pragma unroll
        for (int q = 0; q < 4; ++q) {
            float4 rv = Rp[q], wv = Wp[q];
            r[4*q+0] = rv.x; r[4*q+1] = rv.y; r[4*q+2] = rv.z; r[4*q+3] = rv.w;
            w[4*q+0] = wv.x; w[4*q+1] = wv.y; w[4*q+2] = wv.z; w[4*q+3] = wv.w;
        }
    }
    // each j-half contributes bias/2; the cross-half combine restores full bias
    const float bias_half = 0.5f * bias[h * HD + i];

    float hn = h0[(b * H_SZ + h) * HD + i];   // own row's h (dup in upper half)

    // LDS x-ring: 2 buffers x 16 steps x 32 columns = 4 KB
    __shared__ __align__(16) float xl[2][BLK][32];

    // staging lane map: lane l stages step sk = l>>2, columns sc..sc+7
    const int sk = l >> 2;
    const int sc = (l & 3) * 8;
    const float* xs = x + (long)sk * ST + (long)b * D_SZ + h * HD + sc;

    // bpermute source lanes: h[16p+m] lives in lane 16p+m
    const int bpb = p * 64;

    float* op = out + (long)b * D_SZ + h * HD + i;

    // prologue: stage block 0 into buf 0 (one-time vmcnt stall, fine)
    {
        const float4* g = (const float4*)xs;
        float4 v0 = g[0], v1 = g[1];
        float4* d = (float4*)(&xl[0][sk][sc]);
        d[0] = v0; d[1] = v1;
    }

    for (int tb = 0; tb < T_STEPS; tb += BLK) {
        const int buf  = (tb >> 4) & 1;
        const bool more = (tb + BLK) < T_STEPS;

        // issue next block's global loads early (block top)
        float4 n0, n1;
        if (more) {
            const float4* g = (const float4*)(xs + (long)(tb + BLK) * ST);
            n0 = g[0]; n1 = g[1];
        }

#pragma unroll
        for (int k = 0; k < BLK; ++k) {
            // ---- h gather: issue first (it's the latency op on the chain)
            const int hni = __float_as_int(hn);
            float hr[16];
#pragma unroll
            for (int m = 0; m < 16; ++m)
                hr[m] = __int_as_float(
                    __builtin_amdgcn_ds_bpermute(bpb + 4 * m, hni));

            // ---- x operands from LDS (broadcast, block-early -> off chain)
            float xr[16];
            {
                const float4* xv = (const float4*)(&xl[buf][k][16 * p]);
#pragma unroll
                for (int q = 0; q < 4; ++q) {
                    float4 t4 = xv[q];
                    xr[4*q+0] = t4.x; xr[4*q+1] = t4.y;
                    xr[4*q+2] = t4.z; xr[4*q+3] = t4.w;
                }
            }

            // ---- W-partials (independent of hn; scheduler fills the
            //      bpermute-wait bubbles with these)
            float a0 = fmaf(w[0], xr[0], bias_half);
            float a1 = w[1] * xr[1];
            float a2 = w[2] * xr[2];
            float a3 = w[3] * xr[3];
#pragma unroll
            for (int q = 1; q < 4; ++q) {
                a0 = fmaf(w[4*q+0], xr[4*q+0], a0);
                a1 = fmaf(w[4*q+1], xr[4*q+1], a1);
                a2 = fmaf(w[4*q+2], xr[4*q+2], a2);
                a3 = fmaf(w[4*q+3], xr[4*q+3], a3);
            }
            // ---- R-partials (consume the gathered h)
#pragma unroll
            for (int q = 0; q < 4; ++q) {
                a0 = fmaf(r[4*q+0], hr[4*q+0], a0);
                a1 = fmaf(r[4*q+1], hr[4*q+1], a1);
                a2 = fmaf(r[4*q+2], hr[4*q+2], a2);
                a3 = fmaf(r[4*q+3], hr[4*q+3], a3);
            }
            const float s = (a0 + a1) + (a2 + a3);

            // combine with complementary j-half (proven idiom)
            const float pre = s + __shfl_xor(s, 32, 64);

            // softsign via v_rcp_f32 (~1 ulp; recurrence contractive)
            hn = pre * __builtin_amdgcn_rcpf(1.0f + fabsf(pre));

            // duplicate stores (lane i and 32+i write same value) -> no mask
            op[0] = hn;
            op += ST;
        }

        // block bottom: commit staged data into the other buffer
        if (more) {
            float4* d = (float4*)(&xl[buf ^ 1][sk][sc]);
            d[0] = n0; d[1] = n1;
        }
    }

    // h_final after ys (duplicates identical -> safe)
    out[(long)T_STEPS * ST + (b * H_SZ + h) * HD + i] = hn;
}

extern "C" void kernel_launch(void* const* d_in, const int* in_sizes, int n_in,
                              void* d_out, int out_size, void* d_ws, size_t ws_size,
                              hipStream_t stream) {
    const float* x    = (const float*)d_in[0];
    const float* h0   = (const float*)d_in[1];
    const float* R    = (const float*)d_in[2];
    const float* Wx   = (const float*)d_in[3];
    const float* bias = (const float*)d_in[4];
    float* out = (float*)d_out;

    elman_fused<<<dim3(B_SZ * H_SZ), dim3(64), 0, stream>>>(x, h0, R, Wx, bias, out);
}